// Round 6
// baseline (681.920 us; speedup 1.0000x reference)
//
#include <hip/hip_runtime.h>
#include <hip/hip_fp16.h>
#include <cmath>

// Problem constants
constexpr int B_ = 64, N_ = 50000, L_ = 8, E_ = 100000, U_ = 20000, G_ = 20000, R_ = 64, D_ = 16, C_ = 2;
constexpr int EPL_ = E_ + 3 * U_ + 4096;  // padded edge slots per layer (+slack)
constexpr int EPLG_ = EPL_ / 4 + 64;      // group slots per layer (+64: nu probes past EPL_/4)
constexpr int GPW = 4;                    // groups per wave span (16 edges) — 2x waves vs GPW=8
constexpr int BC = 64;                    // whole batch in one chunk
constexpr int F = BC * 2;                 // float4 chunks per node row (2 KB, fp16)
constexpr int GCAP = EPL_ / 4;
constexpr int SW = (GCAP + GPW - 1) / GPW;  // total wave spans

// h fp16 layout: h[node][b][d], d-contiguous. chunk f = b*2 + dh.
// Node N_ is a reserved all-zero row (padding target).
// ug[g] = u owning edge-group g (groups never straddle u's); -1 past the end.
// ssrc sentinel-filled (N_) over [ptot, ptot+256) and [EPL_-256, EPL_):
// covers all speculative reads (non-clamped < ptot+16; CLG-clamped hit the
// last group). ug memset -1 covers its whole tail.

__device__ __forceinline__ float tanh_fast(float x) {
  float e = __expf(2.0f * x);
  return 1.0f - 2.0f * __builtin_amdgcn_rcpf(e + 1.0f);
}

// ---------------- CSR build (batch-independent) ----------------

__global__ __launch_bounds__(256) void hist_kernel(
    const int* __restrict__ dst_pos, int* __restrict__ cnt,
    int* __restrict__ rank) {
  int e = blockIdx.x * 256 + threadIdx.x;
  int li = blockIdx.y;
  if (e >= E_) return;
  rank[li * E_ + e] = atomicAdd(&cnt[li * U_ + dst_pos[li * E_ + e]], 1);
}

// Light scan only (8 blocks): counts padded to mult of 4, empty u -> 4 slots.
__global__ __launch_bounds__(1024) void scan_kernel(
    const int* __restrict__ cnt, int* __restrict__ offs) {
  __shared__ int sums[1024];
  int li = blockIdx.x, t = threadIdx.x;
  int base = t * 20;
  int v[20];
  int s = 0;
#pragma unroll
  for (int i = 0; i < 20; ++i) {
    int idx = base + i;
    int c = (idx < U_) ? cnt[li * U_ + idx] : -1;
    int pc = (c < 0) ? 0 : ((c == 0) ? 4 : ((c + 3) & ~3));
    v[i] = s;
    s += pc;
  }
  sums[t] = s;
  __syncthreads();
  for (int off = 1; off < 1024; off <<= 1) {
    int o = (t >= off) ? sums[t - off] : 0;
    __syncthreads();
    sums[t] += o;
    __syncthreads();
  }
  int excl = sums[t] - s;
#pragma unroll
  for (int i = 0; i < 20; ++i) {
    int idx = base + i;
    if (idx < U_) offs[li * (U_ + 1) + idx] = excl + v[i];
  }
  if (t == 1023) offs[li * (U_ + 1) + U_] = sums[1023];
}

// Atomic-free scatter: position = offs[u] + precomputed rank.
__global__ __launch_bounds__(256) void scatter_kernel(
    const int* __restrict__ dst_pos, const int* __restrict__ src,
    const int* __restrict__ offs, const int* __restrict__ rank,
    int* __restrict__ ssrc) {
  int e = blockIdx.x * 256 + threadIdx.x;
  int li = blockIdx.y;
  if (e >= E_) return;
  int u = dst_pos[li * E_ + e];
  int p = offs[li * (U_ + 1) + u] + rank[li * E_ + e];
  ssrc[(size_t)li * EPL_ + p] = src[li * E_ + e];
}

// Parallel pad+ug fill + LIGHT ssrc sentinel tails.
// Region A (t < L_*U_): per-u pad sentinels + ug entries.
// Region B (256 threads/layer): sentinel [ptot, ptot+256) + last 256 slots.
__global__ __launch_bounds__(256) void pad_fill_ug_k(
    const int* __restrict__ cnt, const int* __restrict__ offs,
    int* __restrict__ ssrc, int* __restrict__ ug) {
  int t = blockIdx.x * 256 + threadIdx.x;
  if (t < L_ * U_) {
    int li = t / U_, u = t % U_;
    int start = offs[li * (U_ + 1) + u];
    int end = start + cnt[li * U_ + u];       // real end
    int pend = offs[li * (U_ + 1) + u + 1];   // padded end
    int* sp = ssrc + (size_t)li * EPL_;
    for (int p = end; p < pend; ++p) sp[p] = N_;
    int* ugp = ug + (size_t)li * EPLG_;
    for (int g = start >> 2; g < (pend >> 2); ++g) ugp[g] = u;
  } else {
    int t2 = t - L_ * U_;
    int li = t2 >> 8, j = t2 & 255;
    if (li < L_) {
      int* sp = ssrc + (size_t)li * EPL_;
      int ptot = offs[li * (U_ + 1) + U_];
      int pos = ptot + j;
      if (pos < EPL_) sp[pos] = N_;
      sp[EPL_ - 256 + j] = N_;   // clamped speculative reads hit last group
    }
  }
}

// ---------------- Compute ----------------

__global__ __launch_bounds__(256) void gene_init_k(
    const float* __restrict__ X, const float* __restrict__ w_in,
    const float* __restrict__ b_in, const int* __restrict__ gene_map,
    float4* __restrict__ h4) {
  int t = blockIdx.x * 256 + threadIdx.x;
  if (t >= G_ * BC) return;
  int b = t % BC;
  int g = t / BC;
  float x = X[b * G_ + g];
  int node = gene_map[g];
  float4 out[2];
  __half2* oh = reinterpret_cast<__half2*>(out);
#pragma unroll
  for (int k = 0; k < 8; ++k) {
    float r0 = fmaf(x, w_in[2 * k], b_in[2 * k]);
    float r1 = fmaf(x, w_in[2 * k + 1], b_in[2 * k + 1]);
    oh[k] = __float22half2_rn(make_float2(r0, r1));
  }
  h4[(size_t)node * F + b * 2] = out[0];
  h4[(size_t)node * F + b * 2 + 1] = out[1];
}

// Balanced gather-sum, full-batch waves, 3-deep pipeline.
// GPW=4: 11.5K spans -> ~11 blocks/CU queued, up to 8 resident at 44 VGPR —
// doubles wave-level latency hiding vs GPW=8 (round-5 occupancy was 25%).
__global__ __launch_bounds__(256) void gather_k(
    const float4* __restrict__ h4, const int* __restrict__ ug,
    const int* __restrict__ ssrc, float4* __restrict__ agg4, int li) {
  int tid = threadIdx.x;
  int lane = tid & 63;
  int wv = __builtin_amdgcn_readfirstlane(blockIdx.x * 4 + (tid >> 6));
  int g0 = wv * GPW, gend = g0 + GPW;
  const int* ugp = ug + (size_t)li * EPLG_;
  const int* sp = ssrc + (size_t)li * EPL_;

  // prologue: skip tail of the u begun by the previous span
  int prevU = (g0 == 0) ? -2 : ugp[g0 - 1];
  int g = g0;
  while (g < gend && ugp[g] == prevU) ++g;
  if (g >= gend) return;
  int curU = ugp[g];
  if (curU < 0) return;

  // gstop: first group boundary where the last in-span u ends.
  int uend = ugp[gend - 1];
  int gstop;
  if (uend < 0) {
    gstop = g;
    while (ugp[gstop] >= 0) ++gstop;
  } else {
    gstop = gend;
    while (ugp[gstop] == uend) ++gstop;  // -1 tail guarantees termination
  }

  __half2 acc[2][2][4];
  const __half2 z = __half2half2(__float2half(0.f));
#pragma unroll
  for (int j = 0; j < 2; ++j)
#pragma unroll
    for (int r = 0; r < 2; ++r)
#pragma unroll
      for (int k = 0; k < 4; ++k) acc[j][r][k] = z;

  auto flushu = [&](int u) {
#pragma unroll
    for (int r = 0; r < 2; ++r) {
      float4 outv;
      __half2* ov = reinterpret_cast<__half2*>(&outv);
#pragma unroll
      for (int k = 0; k < 4; ++k) {
        float2 f0 = __half22float2(acc[0][r][k]);
        float2 f1 = __half22float2(acc[1][r][k]);
        ov[k] = __float22half2_rn(make_float2(f0.x + f1.x, f0.y + f1.y));
      }
      agg4[(size_t)u * F + lane + r * 64] = outv;
    }
#pragma unroll
    for (int j = 0; j < 2; ++j)
#pragma unroll
      for (int r = 0; r < 2; ++r)
#pragma unroll
        for (int k = 0; k < 4; ++k) acc[j][r][k] = z;
  };

  auto loadRows = [&](float4 (&v)[4][2], int4 id) {
    v[0][0] = h4[(size_t)id.x * F + lane]; v[0][1] = h4[(size_t)id.x * F + lane + 64];
    v[1][0] = h4[(size_t)id.y * F + lane]; v[1][1] = h4[(size_t)id.y * F + lane + 64];
    v[2][0] = h4[(size_t)id.z * F + lane]; v[2][1] = h4[(size_t)id.z * F + lane + 64];
    v[3][0] = h4[(size_t)id.w * F + lane]; v[3][1] = h4[(size_t)id.w * F + lane + 64];
  };
  auto accum = [&](const float4 (&v)[4][2]) {
#pragma unroll
    for (int j = 0; j < 4; ++j)
#pragma unroll
      for (int r = 0; r < 2; ++r) {
        const __half2* p = reinterpret_cast<const __half2*>(&v[j][r]);
#pragma unroll
        for (int k = 0; k < 4; ++k)
          acc[j & 1][r][k] = __hadd2(acc[j & 1][r][k], p[k]);
      }
  };

  auto CLG = [&](int q) { return (q < GCAP) ? q : GCAP - 1; };

  // pipeline prologue: rows for g, g+1 in flight; ids for g+2, g+3 staged;
  // nu for g, g+1, g+2 staged.
  int4 id0 = *(const int4*)(sp + 4 * g);
  int4 id1 = *(const int4*)(sp + 4 * CLG(g + 1));
  int4 idP = *(const int4*)(sp + 4 * CLG(g + 2));
  int4 idQ = *(const int4*)(sp + 4 * CLG(g + 3));
  int4 idR;
  int nuA = ugp[g + 1];
  int nuB = ugp[CLG(g + 1) + 1];
  int nuC = ugp[CLG(g + 2) + 1];

  float4 va[4][2], vb[4][2], vc[4][2];
  loadRows(va, id0);
  loadRows(vb, id1);

  // Phase for group g: issue rows(g+2) from an id loaded 2 phases ago,
  // prefetch id(g+4) and nu(g+3), accumulate rows(g), flush on u-change.
#define PHASE(VACC, VLD, IDLD, IDPF, NUCUR)          \
  {                                                  \
    loadRows(VLD, IDLD);                             \
    IDPF = *(const int4*)(sp + 4 * CLG(g + 4));      \
    int nuCur = NUCUR;                               \
    NUCUR = ugp[CLG(g + 3) + 1];                     \
    accum(VACC);                                     \
    if (nuCur != curU) {                             \
      flushu(curU);                                  \
      if (g + 1 >= gstop) return;                    \
      curU = nuCur;                                  \
    }                                                \
    ++g;                                             \
  }

  for (;;) {
    PHASE(va, vc, idP, idR, nuA)
    PHASE(vb, va, idQ, idP, nuB)
    PHASE(vc, vb, idR, idQ, nuC)
  }
#undef PHASE
}

// Dense epilogue: one thread per (u,b). All-static indexing (no scratch).
__global__ __launch_bounds__(256) void dense_k(
    const float4* __restrict__ agg4, const float* __restrict__ W,
    const float* __restrict__ bias, const int* __restrict__ dst_unique,
    float4* __restrict__ h4, int li) {
  __shared__ float Wlds[256];
  int tid = threadIdx.x;
  Wlds[tid] = W[li * 256 + tid];
  __syncthreads();
  int u = __builtin_amdgcn_readfirstlane(blockIdx.x * 4 + (tid >> 6));
  int b = tid & 63;
  float4 c0 = agg4[(size_t)u * F + b * 2];
  float4 c1 = agg4[(size_t)u * F + b * 2 + 1];
  float a[16];
  {
    const __half2* p0 = reinterpret_cast<const __half2*>(&c0);
    const __half2* p1 = reinterpret_cast<const __half2*>(&c1);
#pragma unroll
    for (int k = 0; k < 4; ++k) {
      float2 f0 = __half22float2(p0[k]);
      float2 f1 = __half22float2(p1[k]);
      a[2 * k] = f0.x; a[2 * k + 1] = f0.y;
      a[8 + 2 * k] = f1.x; a[8 + 2 * k + 1] = f1.y;
    }
  }
  float m[16];
#pragma unroll
  for (int j = 0; j < 16; ++j) m[j] = 0.f;
#pragma unroll
  for (int d = 0; d < 16; ++d) {
    float s = a[d];
    const float4* wr = (const float4*)&Wlds[d * 16];  // broadcast reads (free)
    float4 w0 = wr[0], w1 = wr[1], w2 = wr[2], w3 = wr[3];
    m[0] = fmaf(s, w0.x, m[0]);  m[1] = fmaf(s, w0.y, m[1]);
    m[2] = fmaf(s, w0.z, m[2]);  m[3] = fmaf(s, w0.w, m[3]);
    m[4] = fmaf(s, w1.x, m[4]);  m[5] = fmaf(s, w1.y, m[5]);
    m[6] = fmaf(s, w1.z, m[6]);  m[7] = fmaf(s, w1.w, m[7]);
    m[8] = fmaf(s, w2.x, m[8]);  m[9] = fmaf(s, w2.y, m[9]);
    m[10] = fmaf(s, w2.z, m[10]); m[11] = fmaf(s, w2.w, m[11]);
    m[12] = fmaf(s, w3.x, m[12]); m[13] = fmaf(s, w3.y, m[13]);
    m[14] = fmaf(s, w3.z, m[14]); m[15] = fmaf(s, w3.w, m[15]);
  }
  int node = dst_unique[li * U_ + u];  // wave-uniform (scalar)
  const float4* bp = (const float4*)(bias + (size_t)node * 16);
  float4 b0 = bp[0], b1 = bp[1], b2 = bp[2], b3 = bp[3];
  float bb[16] = {b0.x, b0.y, b0.z, b0.w, b1.x, b1.y, b1.z, b1.w,
                  b2.x, b2.y, b2.z, b2.w, b3.x, b3.y, b3.z, b3.w};
  float4 o0, o1;
  __half2* ov0 = reinterpret_cast<__half2*>(&o0);
  __half2* ov1 = reinterpret_cast<__half2*>(&o1);
#pragma unroll
  for (int k = 0; k < 4; ++k) {
    ov0[k] = __float22half2_rn(make_float2(tanh_fast(m[2 * k] + bb[2 * k]),
                                           tanh_fast(m[2 * k + 1] + bb[2 * k + 1])));
    ov1[k] = __float22half2_rn(make_float2(tanh_fast(m[8 + 2 * k] + bb[8 + 2 * k]),
                                           tanh_fast(m[8 + 2 * k + 1] + bb[8 + 2 * k + 1])));
  }
  h4[(size_t)node * F + b * 2] = o0;
  h4[(size_t)node * F + b * 2 + 1] = o1;
}

__global__ __launch_bounds__(64) void head_k(
    const float4* __restrict__ h4, const float* __restrict__ W_head,
    const float* __restrict__ b_head, const int* __restrict__ root_ids,
    float* __restrict__ out) {
  int bl = blockIdx.x;
  int r = threadIdx.x;
  int node = root_ids[r];
  float4 p0 = h4[(size_t)node * F + bl * 2];
  float4 p1 = h4[(size_t)node * F + bl * 2 + 1];
  float v[16];
  const __half2* ph0 = reinterpret_cast<const __half2*>(&p0);
  const __half2* ph1 = reinterpret_cast<const __half2*>(&p1);
#pragma unroll
  for (int k = 0; k < 4; ++k) {
    float2 f0 = __half22float2(ph0[k]);
    float2 f1 = __half22float2(ph1[k]);
    v[2 * k] = f0.x; v[2 * k + 1] = f0.y;
    v[8 + 2 * k] = f1.x; v[8 + 2 * k + 1] = f1.y;
  }
  float acc0 = 0.f, acc1 = 0.f;
#pragma unroll
  for (int d = 0; d < 16; ++d) {
    acc0 = fmaf(v[d], W_head[r * 16 + d], acc0);
    acc1 = fmaf(v[d], W_head[1024 + r * 16 + d], acc1);
  }
  for (int off = 32; off; off >>= 1) {
    acc0 += __shfl_down(acc0, off, 64);
    acc1 += __shfl_down(acc1, off, 64);
  }
  if (r == 0) {
    out[bl * 2 + 0] = acc0 + b_head[0];
    out[bl * 2 + 1] = acc1 + b_head[1];
  }
}

__global__ void zero_out_k(float* out, int n) {
  int t = blockIdx.x * 256 + threadIdx.x;
  if (t < n) out[t] = 0.f;
}

// ---------------- Host side ----------------

static size_t need_bytes() {
  return (size_t)(N_ + 1) * F * 16 + (size_t)U_ * F * 16 +
         (size_t)L_ * U_ * 4 +            // cnt
         (size_t)L_ * (U_ + 1) * 4 +      // offs
         (size_t)L_ * E_ * 4 +            // rank
         (size_t)L_ * EPL_ * 4 +          // ssrc
         (size_t)L_ * EPLG_ * 4;          // ug
}

extern "C" void kernel_launch(void* const* d_in, const int* in_sizes, int n_in,
                              void* d_out, int out_size, void* d_ws, size_t ws_size,
                              hipStream_t stream) {
  if (ws_size < need_bytes()) {
    zero_out_k<<<(out_size + 255) / 256, 256, 0, stream>>>((float*)d_out, out_size);
    return;
  }
  const float* X = (const float*)d_in[0];
  const float* w_in = (const float*)d_in[1];
  const float* b_in = (const float*)d_in[2];
  const float* W = (const float*)d_in[3];
  const float* bias = (const float*)d_in[4];
  const float* W_head = (const float*)d_in[5];
  const float* b_head = (const float*)d_in[6];
  const int* gene_map = (const int*)d_in[7];
  const int* src = (const int*)d_in[8];
  const int* dst_pos = (const int*)d_in[9];
  const int* dst_unique = (const int*)d_in[10];
  const int* root_ids = (const int*)d_in[11];
  float* out = (float*)d_out;

  const size_t h_bytes = (size_t)(N_ + 1) * F * 16;  // + zero sentinel row
  const size_t agg_bytes = (size_t)U_ * F * 16;
  const size_t cnt_bytes = (size_t)L_ * U_ * 4;
  const size_t offs_bytes = (size_t)L_ * (U_ + 1) * 4;
  const size_t rank_bytes = (size_t)L_ * E_ * 4;
  const size_t ssrc_bytes = (size_t)L_ * EPL_ * 4;
  const size_t ug_bytes = (size_t)L_ * EPLG_ * 4;

  char* ws = (char*)d_ws;
  float4* h4 = (float4*)ws;
  float4* agg4 = (float4*)(ws + h_bytes);
  int* cnt = (int*)(ws + h_bytes + agg_bytes);
  int* offs = (int*)(ws + h_bytes + agg_bytes + cnt_bytes);
  int* rank = (int*)(ws + h_bytes + agg_bytes + cnt_bytes + offs_bytes);
  int* ssrc = (int*)(ws + h_bytes + agg_bytes + cnt_bytes + offs_bytes + rank_bytes);
  int* ug = (int*)(ws + h_bytes + agg_bytes + cnt_bytes + offs_bytes + rank_bytes + ssrc_bytes);

  hipMemsetAsync(cnt, 0, cnt_bytes, stream);
  hipMemsetAsync(ug, 0xFF, ug_bytes, stream);  // -1 sentinels incl. tails
  hipMemsetAsync(h4, 0, h_bytes, stream);
  dim3 egrid((E_ + 255) / 256, L_);
  hist_kernel<<<egrid, 256, 0, stream>>>(dst_pos, cnt, rank);
  scan_kernel<<<L_, 1024, 0, stream>>>(cnt, offs);
  scatter_kernel<<<egrid, 256, 0, stream>>>(dst_pos, src, offs, rank, ssrc);
  const int pf_grid = (L_ * U_ + L_ * 256 + 255) / 256;
  pad_fill_ug_k<<<pf_grid, 256, 0, stream>>>(cnt, offs, ssrc, ug);

  gene_init_k<<<(G_ * BC + 255) / 256, 256, 0, stream>>>(X, w_in, b_in, gene_map, h4);

  const int gather_grid = (SW + 3) / 4;
  const int dense_grid = U_ * BC / 256;
  for (int li = 0; li < L_; ++li) {
    gather_k<<<gather_grid, 256, 0, stream>>>(h4, ug, ssrc, agg4, li);
    dense_k<<<dense_grid, 256, 0, stream>>>(agg4, W, bias, dst_unique, h4, li);
  }

  head_k<<<BC, 64, 0, stream>>>(h4, W_head, b_head, root_ids, out);
}

// Round 8
// 550.722 us; speedup vs baseline: 1.2382x; 1.2382x over previous
//
#include <hip/hip_runtime.h>
#include <hip/hip_fp16.h>
#include <cmath>

// Problem constants
constexpr int B_ = 64, N_ = 50000, L_ = 8, E_ = 100000, U_ = 20000, G_ = 20000, R_ = 64, D_ = 16, C_ = 2;
constexpr int EPL_ = E_ + 3 * U_ + 4096;  // padded edge slots per layer
constexpr int EPLG_ = EPL_ / 4 + 64;      // group slots per layer (+64: nu probes past EPL_/4)
constexpr int GPW = 8;                    // groups per wave span (32 edges)
constexpr int GCAP = EPL_ / 4;
constexpr int SW = (GCAP + GPW - 1) / GPW;

// Classic geometry (fallback): full batch, 2 KB rows.
constexpr int BC = 64;
constexpr int F = BC * 2;                 // 128 float4 chunks/row

// Arena geometry: HALF batch, 1 KB rows -> versioned arena fits 256 MiB ws.
// phys row 0 = zero row; rows 1..G = gene rows; row DST0+li*U+u = layer-li
// output for dst index u. ssrc remapped to rows valid BEFORE layer li ->
// same-layer reads/writes disjoint (no race). Two passes over batch halves.
constexpr int HBC = 32;
constexpr int FH = HBC * 2;               // 64 float4 chunks/row (1 KB)
constexpr int DST0 = 1 + G_;
constexpr int AROWS = DST0 + L_ * U_;     // 180001 rows = 184.3 MB

__device__ __forceinline__ float tanh_fast(float x) {
  float e = __expf(2.0f * x);
  return 1.0f - 2.0f * __builtin_amdgcn_rcpf(e + 1.0f);
}

// ---------------- CSR build (batch-independent, shared) ----------------

__global__ __launch_bounds__(256) void hist_kernel(
    const int* __restrict__ dst_pos, int* __restrict__ cnt,
    int* __restrict__ rank) {
  int e = blockIdx.x * 256 + threadIdx.x;
  int li = blockIdx.y;
  if (e >= E_) return;
  rank[li * E_ + e] = atomicAdd(&cnt[li * U_ + dst_pos[li * E_ + e]], 1);
}

__global__ __launch_bounds__(1024) void scan_kernel(
    const int* __restrict__ cnt, int* __restrict__ offs) {
  __shared__ int sums[1024];
  int li = blockIdx.x, t = threadIdx.x;
  int base = t * 20;
  int v[20];
  int s = 0;
#pragma unroll
  for (int i = 0; i < 20; ++i) {
    int idx = base + i;
    int c = (idx < U_) ? cnt[li * U_ + idx] : -1;
    int pc = (c < 0) ? 0 : ((c == 0) ? 4 : ((c + 3) & ~3));
    v[i] = s;
    s += pc;
  }
  sums[t] = s;
  __syncthreads();
  for (int off = 1; off < 1024; off <<= 1) {
    int o = (t >= off) ? sums[t - off] : 0;
    __syncthreads();
    sums[t] += o;
    __syncthreads();
  }
  int excl = sums[t] - s;
#pragma unroll
  for (int i = 0; i < 20; ++i) {
    int idx = base + i;
    if (idx < U_) offs[li * (U_ + 1) + idx] = excl + v[i];
  }
  if (t == 1023) offs[li * (U_ + 1) + U_] = sums[1023];
}

__global__ __launch_bounds__(256) void scatter_kernel(
    const int* __restrict__ dst_pos, const int* __restrict__ src,
    const int* __restrict__ offs, const int* __restrict__ rank,
    int* __restrict__ ssrc) {
  int e = blockIdx.x * 256 + threadIdx.x;
  int li = blockIdx.y;
  if (e >= E_) return;
  int u = dst_pos[li * E_ + e];
  int p = offs[li * (U_ + 1) + u] + rank[li * E_ + e];
  ssrc[(size_t)li * EPL_ + p] = src[li * E_ + e];
}

// Pad+ug fill + light ssrc sentinel tails ([ptot,ptot+256) + last 256 slots).
__global__ __launch_bounds__(256) void pad_fill_ug_k(
    const int* __restrict__ cnt, const int* __restrict__ offs,
    int* __restrict__ ssrc, int* __restrict__ ug) {
  int t = blockIdx.x * 256 + threadIdx.x;
  if (t < L_ * U_) {
    int li = t / U_, u = t % U_;
    int start = offs[li * (U_ + 1) + u];
    int end = start + cnt[li * U_ + u];
    int pend = offs[li * (U_ + 1) + u + 1];
    int* sp = ssrc + (size_t)li * EPL_;
    for (int p = end; p < pend; ++p) sp[p] = N_;
    int* ugp = ug + (size_t)li * EPLG_;
    for (int g = start >> 2; g < (pend >> 2); ++g) ugp[g] = u;
  } else {
    int t2 = t - L_ * U_;
    int li = t2 >> 8, j = t2 & 255;
    if (li < L_) {
      int* sp = ssrc + (size_t)li * EPL_;
      int ptot = offs[li * (U_ + 1) + U_];
      int pos = ptot + j;
      if (pos < EPL_) sp[pos] = N_;
      sp[EPL_ - 256 + j] = N_;
    }
  }
}

// ---------------- Arena versioning build ----------------

// wmask[n] = bitmask of layers writing node n; posarr[li*N+n] = u index;
// lw0[n] = pre-layer phys row (gene row or 0). wmask/lw0 pre-zeroed.
__global__ __launch_bounds__(256) void mark_k(
    const int* __restrict__ dst_unique, const int* __restrict__ gene_map,
    int* __restrict__ wmask, int* __restrict__ posarr, int* __restrict__ lw0) {
  int t = blockIdx.x * 256 + threadIdx.x;
  if (t < L_ * U_) {
    int li = t / U_, u = t % U_;
    int n = dst_unique[t];
    posarr[li * N_ + n] = u;
    atomicOr(&wmask[n], 1 << li);
  } else {
    int g = t - L_ * U_;
    if (g < G_) lw0[gene_map[g]] = 1 + g;
  }
}

// Remap ssrc node-ids -> phys rows valid BEFORE layer li. Touches only
// initialized slots (p < ptot+256 or p >= EPL_-256).
__global__ __launch_bounds__(256) void remap_k(
    const int* __restrict__ offs, const int* __restrict__ wmask,
    const int* __restrict__ posarr, const int* __restrict__ lw0,
    int* __restrict__ ssrc) {
  int p = blockIdx.x * 256 + threadIdx.x;
  int li = blockIdx.y;
  if (p >= EPL_) return;
  int ptot = offs[li * (U_ + 1) + U_];
  if (p >= ptot + 256 && p < EPL_ - 256) return;
  int* sp = ssrc + (size_t)li * EPL_;
  int s = sp[p];  // node id in [0, N_]; sentinel N_ -> wmask/lw0 = 0 -> row 0
  int m = wmask[s] & ((1 << li) - 1);
  int phys;
  if (m) {
    int lj = 31 - __clz(m);
    phys = DST0 + lj * U_ + posarr[lj * N_ + s];
  } else {
    phys = lw0[s];
  }
  sp[p] = phys;
}

// ---------------- Shared gather phase macro ----------------
#define PHASE(VACC, VLD, IDLD, IDPF, NUCUR)          \
  {                                                  \
    loadRows(VLD, IDLD);                             \
    IDPF = *(const int4*)(sp + 4 * CLG(g + 4));      \
    int nuCur = NUCUR;                               \
    NUCUR = ugp[CLG(g + 3) + 1];                     \
    accum(VACC);                                     \
    if (nuCur != curU) {                             \
      flushu(curU);                                  \
      if (g + 1 >= gstop) return;                    \
      curU = nuCur;                                  \
    }                                                \
    ++g;                                             \
  }

// ---------------- Arena-path compute (half batch, 1 KB rows) ----------------

// Gene init: writes rows 1..G for batch half `half` (chunks b*2, b*2+1).
__global__ __launch_bounds__(256) void gene_a(
    const float* __restrict__ X, const float* __restrict__ w_in,
    const float* __restrict__ b_in, float4* __restrict__ h4, int half) {
  int t = blockIdx.x * 256 + threadIdx.x;
  if (t >= G_ * HBC) return;
  int b = t % HBC;
  int g = t / HBC;
  float x = X[(half * HBC + b) * G_ + g];
  float4 out[2];
  __half2* oh = reinterpret_cast<__half2*>(out);
#pragma unroll
  for (int k = 0; k < 8; ++k) {
    float r0 = fmaf(x, w_in[2 * k], b_in[2 * k]);
    float r1 = fmaf(x, w_in[2 * k + 1], b_in[2 * k + 1]);
    oh[k] = __float22half2_rn(make_float2(r0, r1));
  }
  h4[(size_t)(1 + g) * FH + b * 2] = out[0];
  h4[(size_t)(1 + g) * FH + b * 2 + 1] = out[1];
}

// Fused gather+dense: accumulate fp16 sums per u, then at flush apply the
// 16x16 W matmul (split across lane pairs), bias, tanh, and write the
// versioned arena row directly. One float4 chunk per lane per row.
__global__ __launch_bounds__(256, 2) void gfused_a(
    const float4* __restrict__ h4, const int* __restrict__ ug,
    const int* __restrict__ ssrc, const float* __restrict__ W,
    const float* __restrict__ bias, const int* __restrict__ dst_unique,
    float4* __restrict__ o4, int li) {
  __shared__ float Wlds[256];
  int tid = threadIdx.x;
  Wlds[tid] = W[li * 256 + tid];
  __syncthreads();
  int lane = tid & 63;
  int dh = lane & 1;  // chunk = lane: batch b = lane>>1, d-half dh
  int wv = __builtin_amdgcn_readfirstlane(blockIdx.x * 4 + (tid >> 6));
  const int* ugp = ug + (size_t)li * EPLG_;
  const int* sp = ssrc + (size_t)li * EPL_;
  const int* du = dst_unique + (size_t)li * U_;

  int g0 = wv * GPW, gend = g0 + GPW;
  int prevU = (g0 == 0) ? -2 : ugp[g0 - 1];
  int g = g0;
  while (g < gend && ugp[g] == prevU) ++g;
  if (g >= gend) return;
  int curU = ugp[g];
  if (curU < 0) return;
  int uend = ugp[gend - 1];
  int gstop;
  if (uend < 0) {
    gstop = g;
    while (ugp[gstop] >= 0) ++gstop;
  } else {
    gstop = gend;
    while (ugp[gstop] == uend) ++gstop;
  }

  __half2 acc[2][4];
  const __half2 z = __half2half2(__float2half(0.f));
#pragma unroll
  for (int j = 0; j < 2; ++j)
#pragma unroll
    for (int k = 0; k < 4; ++k) acc[j][k] = z;

  auto flushu = [&](int u) {
    int node = du[u];  // wave-uniform
    float biasv[8];
    {
      const float4* bp = (const float4*)(bias + (size_t)node * 16 + dh * 8);
      float4 q0 = bp[0], q1 = bp[1];
      biasv[0] = q0.x; biasv[1] = q0.y; biasv[2] = q0.z; biasv[3] = q0.w;
      biasv[4] = q1.x; biasv[5] = q1.y; biasv[6] = q1.z; biasv[7] = q1.w;
    }
    // fp16-rounded aggregate (bit-identical to classic agg roundtrip)
    float a8[8];
#pragma unroll
    for (int k = 0; k < 4; ++k) {
      float2 f0 = __half22float2(acc[0][k]);
      float2 f1 = __half22float2(acc[1][k]);
      __half2 hv = __float22half2_rn(make_float2(f0.x + f1.x, f0.y + f1.y));
      float2 fa = __half22float2(hv);
      a8[2 * k] = fa.x; a8[2 * k + 1] = fa.y;
    }
    // partial matmul over this lane's 8 d's
    float pm[16];
#pragma unroll
    for (int j = 0; j < 16; ++j) pm[j] = 0.f;
#pragma unroll
    for (int dd = 0; dd < 8; ++dd) {
      float s = a8[dd];
      const float4* wr = (const float4*)&Wlds[(dh * 8 + dd) * 16];
      float4 w0 = wr[0], w1 = wr[1], w2 = wr[2], w3 = wr[3];
      pm[0] = fmaf(s, w0.x, pm[0]);  pm[1] = fmaf(s, w0.y, pm[1]);
      pm[2] = fmaf(s, w0.z, pm[2]);  pm[3] = fmaf(s, w0.w, pm[3]);
      pm[4] = fmaf(s, w1.x, pm[4]);  pm[5] = fmaf(s, w1.y, pm[5]);
      pm[6] = fmaf(s, w1.z, pm[6]);  pm[7] = fmaf(s, w1.w, pm[7]);
      pm[8] = fmaf(s, w2.x, pm[8]);  pm[9] = fmaf(s, w2.y, pm[9]);
      pm[10] = fmaf(s, w2.z, pm[10]); pm[11] = fmaf(s, w2.w, pm[11]);
      pm[12] = fmaf(s, w3.x, pm[12]); pm[13] = fmaf(s, w3.y, pm[13]);
      pm[14] = fmaf(s, w3.z, pm[14]); pm[15] = fmaf(s, w3.w, pm[15]);
    }
    // partner lane (lane^1) holds the other 8 d's of the same batch
    float m8[8];
#pragma unroll
    for (int jj = 0; jj < 8; ++jj) {
      float s0 = pm[jj] + __shfl_xor(pm[jj], 1, 64);
      float s1 = pm[8 + jj] + __shfl_xor(pm[8 + jj], 1, 64);
      m8[jj] = dh ? s1 : s0;
    }
    float4 outv;
    __half2* ov = reinterpret_cast<__half2*>(&outv);
#pragma unroll
    for (int k = 0; k < 4; ++k) {
      ov[k] = __float22half2_rn(
          make_float2(tanh_fast(m8[2 * k] + biasv[2 * k]),
                      tanh_fast(m8[2 * k + 1] + biasv[2 * k + 1])));
    }
    o4[(size_t)(DST0 + li * U_ + u) * FH + lane] = outv;
#pragma unroll
    for (int j = 0; j < 2; ++j)
#pragma unroll
      for (int k = 0; k < 4; ++k) acc[j][k] = z;
  };

  auto loadRows = [&](float4 (&v)[4], int4 id) {
    v[0] = h4[(size_t)id.x * FH + lane];
    v[1] = h4[(size_t)id.y * FH + lane];
    v[2] = h4[(size_t)id.z * FH + lane];
    v[3] = h4[(size_t)id.w * FH + lane];
  };
  auto accum = [&](const float4 (&v)[4]) {
#pragma unroll
    for (int j = 0; j < 4; ++j) {
      const __half2* p = reinterpret_cast<const __half2*>(&v[j]);
#pragma unroll
      for (int k = 0; k < 4; ++k)
        acc[j & 1][k] = __hadd2(acc[j & 1][k], p[k]);
    }
  };
  auto CLG = [&](int q) { return (q < GCAP) ? q : GCAP - 1; };

  int4 id0 = *(const int4*)(sp + 4 * g);
  int4 id1 = *(const int4*)(sp + 4 * CLG(g + 1));
  int4 idP = *(const int4*)(sp + 4 * CLG(g + 2));
  int4 idQ = *(const int4*)(sp + 4 * CLG(g + 3));
  int4 idR;
  int nuA = ugp[g + 1];
  int nuB = ugp[CLG(g + 1) + 1];
  int nuC = ugp[CLG(g + 2) + 1];

  float4 va[4], vb[4], vc[4];
  loadRows(va, id0);
  loadRows(vb, id1);

  for (;;) {
    PHASE(va, vc, idP, idR, nuA)
    PHASE(vb, va, idQ, idP, nuB)
    PHASE(vc, vb, idR, idQ, nuC)
  }
}

// Head for one batch half: resolve final version per root via wmask.
__global__ __launch_bounds__(64) void head_a(
    const float4* __restrict__ h4, const float* __restrict__ W_head,
    const float* __restrict__ b_head, const int* __restrict__ root_ids,
    const int* __restrict__ wmask, const int* __restrict__ posarr,
    const int* __restrict__ lw0, int half, float* __restrict__ out) {
  int bl = blockIdx.x;  // 0..HBC-1
  int r = threadIdx.x;
  int node = root_ids[r];
  int m = wmask[node];
  int phys;
  if (m) {
    int lj = 31 - __clz(m);
    phys = DST0 + lj * U_ + posarr[lj * N_ + node];
  } else {
    phys = lw0[node];
  }
  float4 p0 = h4[(size_t)phys * FH + bl * 2];
  float4 p1 = h4[(size_t)phys * FH + bl * 2 + 1];
  float v[16];
  const __half2* ph0 = reinterpret_cast<const __half2*>(&p0);
  const __half2* ph1 = reinterpret_cast<const __half2*>(&p1);
#pragma unroll
  for (int k = 0; k < 4; ++k) {
    float2 f0 = __half22float2(ph0[k]);
    float2 f1 = __half22float2(ph1[k]);
    v[2 * k] = f0.x; v[2 * k + 1] = f0.y;
    v[8 + 2 * k] = f1.x; v[8 + 2 * k + 1] = f1.y;
  }
  float acc0 = 0.f, acc1 = 0.f;
#pragma unroll
  for (int d = 0; d < 16; ++d) {
    acc0 = fmaf(v[d], W_head[r * 16 + d], acc0);
    acc1 = fmaf(v[d], W_head[1024 + r * 16 + d], acc1);
  }
  for (int off = 32; off; off >>= 1) {
    acc0 += __shfl_down(acc0, off, 64);
    acc1 += __shfl_down(acc1, off, 64);
  }
  if (r == 0) {
    int gb = half * HBC + bl;
    out[gb * 2 + 0] = acc0 + b_head[0];
    out[gb * 2 + 1] = acc1 + b_head[1];
  }
}

// ---------------- Classic fallback (round-5 proven, 2 KB rows) --------------

__global__ __launch_bounds__(256) void gene_c(
    const float* __restrict__ X, const float* __restrict__ w_in,
    const float* __restrict__ b_in, const int* __restrict__ gene_map,
    float4* __restrict__ h4) {
  int t = blockIdx.x * 256 + threadIdx.x;
  if (t >= G_ * BC) return;
  int b = t % BC;
  int g = t / BC;
  float x = X[b * G_ + g];
  int node = gene_map[g];
  float4 out[2];
  __half2* oh = reinterpret_cast<__half2*>(out);
#pragma unroll
  for (int k = 0; k < 8; ++k) {
    float r0 = fmaf(x, w_in[2 * k], b_in[2 * k]);
    float r1 = fmaf(x, w_in[2 * k + 1], b_in[2 * k + 1]);
    oh[k] = __float22half2_rn(make_float2(r0, r1));
  }
  h4[(size_t)node * F + b * 2] = out[0];
  h4[(size_t)node * F + b * 2 + 1] = out[1];
}

__global__ __launch_bounds__(256, 2) void gather_c(
    const float4* __restrict__ h4, const int* __restrict__ ug,
    const int* __restrict__ ssrc, float4* __restrict__ agg4, int li) {
  int tid = threadIdx.x;
  int lane = tid & 63;
  int wv = __builtin_amdgcn_readfirstlane(blockIdx.x * 4 + (tid >> 6));
  const int* ugp = ug + (size_t)li * EPLG_;
  const int* sp = ssrc + (size_t)li * EPL_;

  int g0 = wv * GPW, gend = g0 + GPW;
  int prevU = (g0 == 0) ? -2 : ugp[g0 - 1];
  int g = g0;
  while (g < gend && ugp[g] == prevU) ++g;
  if (g >= gend) return;
  int curU = ugp[g];
  if (curU < 0) return;
  int uend = ugp[gend - 1];
  int gstop;
  if (uend < 0) {
    gstop = g;
    while (ugp[gstop] >= 0) ++gstop;
  } else {
    gstop = gend;
    while (ugp[gstop] == uend) ++gstop;
  }

  __half2 acc[2][2][4];
  const __half2 z = __half2half2(__float2half(0.f));
#pragma unroll
  for (int j = 0; j < 2; ++j)
#pragma unroll
    for (int r = 0; r < 2; ++r)
#pragma unroll
      for (int k = 0; k < 4; ++k) acc[j][r][k] = z;

  auto flushu = [&](int u) {
#pragma unroll
    for (int r = 0; r < 2; ++r) {
      float4 outv;
      __half2* ov = reinterpret_cast<__half2*>(&outv);
#pragma unroll
      for (int k = 0; k < 4; ++k) {
        float2 f0 = __half22float2(acc[0][r][k]);
        float2 f1 = __half22float2(acc[1][r][k]);
        ov[k] = __float22half2_rn(make_float2(f0.x + f1.x, f0.y + f1.y));
      }
      agg4[(size_t)u * F + lane + r * 64] = outv;
    }
#pragma unroll
    for (int j = 0; j < 2; ++j)
#pragma unroll
      for (int r = 0; r < 2; ++r)
#pragma unroll
        for (int k = 0; k < 4; ++k) acc[j][r][k] = z;
  };
  auto loadRows = [&](float4 (&v)[4][2], int4 id) {
    v[0][0] = h4[(size_t)id.x * F + lane]; v[0][1] = h4[(size_t)id.x * F + lane + 64];
    v[1][0] = h4[(size_t)id.y * F + lane]; v[1][1] = h4[(size_t)id.y * F + lane + 64];
    v[2][0] = h4[(size_t)id.z * F + lane]; v[2][1] = h4[(size_t)id.z * F + lane + 64];
    v[3][0] = h4[(size_t)id.w * F + lane]; v[3][1] = h4[(size_t)id.w * F + lane + 64];
  };
  auto accum = [&](const float4 (&v)[4][2]) {
#pragma unroll
    for (int j = 0; j < 4; ++j)
#pragma unroll
      for (int r = 0; r < 2; ++r) {
        const __half2* p = reinterpret_cast<const __half2*>(&v[j][r]);
#pragma unroll
        for (int k = 0; k < 4; ++k)
          acc[j & 1][r][k] = __hadd2(acc[j & 1][r][k], p[k]);
      }
  };
  auto CLG = [&](int q) { return (q < GCAP) ? q : GCAP - 1; };

  int4 id0 = *(const int4*)(sp + 4 * g);
  int4 id1 = *(const int4*)(sp + 4 * CLG(g + 1));
  int4 idP = *(const int4*)(sp + 4 * CLG(g + 2));
  int4 idQ = *(const int4*)(sp + 4 * CLG(g + 3));
  int4 idR;
  int nuA = ugp[g + 1];
  int nuB = ugp[CLG(g + 1) + 1];
  int nuC = ugp[CLG(g + 2) + 1];

  float4 va[4][2], vb[4][2], vc[4][2];
  loadRows(va, id0);
  loadRows(vb, id1);

  for (;;) {
    PHASE(va, vc, idP, idR, nuA)
    PHASE(vb, va, idQ, idP, nuB)
    PHASE(vc, vb, idR, idQ, nuC)
  }
}
#undef PHASE

__global__ __launch_bounds__(256) void dense_c(
    const float4* __restrict__ agg4, const float* __restrict__ W,
    const float* __restrict__ bias, const int* __restrict__ dst_unique,
    float4* __restrict__ h4, int li) {
  __shared__ float Wlds[256];
  int tid = threadIdx.x;
  Wlds[tid] = W[li * 256 + tid];
  __syncthreads();
  int u = __builtin_amdgcn_readfirstlane(blockIdx.x * 4 + (tid >> 6));
  int b = tid & 63;
  float4 c0 = agg4[(size_t)u * F + b * 2];
  float4 c1 = agg4[(size_t)u * F + b * 2 + 1];
  float a[16];
  {
    const __half2* p0 = reinterpret_cast<const __half2*>(&c0);
    const __half2* p1 = reinterpret_cast<const __half2*>(&c1);
#pragma unroll
    for (int k = 0; k < 4; ++k) {
      float2 f0 = __half22float2(p0[k]);
      float2 f1 = __half22float2(p1[k]);
      a[2 * k] = f0.x; a[2 * k + 1] = f0.y;
      a[8 + 2 * k] = f1.x; a[8 + 2 * k + 1] = f1.y;
    }
  }
  float m[16];
#pragma unroll
  for (int j = 0; j < 16; ++j) m[j] = 0.f;
#pragma unroll
  for (int d = 0; d < 16; ++d) {
    float s = a[d];
    const float4* wr = (const float4*)&Wlds[d * 16];
    float4 w0 = wr[0], w1 = wr[1], w2 = wr[2], w3 = wr[3];
    m[0] = fmaf(s, w0.x, m[0]);  m[1] = fmaf(s, w0.y, m[1]);
    m[2] = fmaf(s, w0.z, m[2]);  m[3] = fmaf(s, w0.w, m[3]);
    m[4] = fmaf(s, w1.x, m[4]);  m[5] = fmaf(s, w1.y, m[5]);
    m[6] = fmaf(s, w1.z, m[6]);  m[7] = fmaf(s, w1.w, m[7]);
    m[8] = fmaf(s, w2.x, m[8]);  m[9] = fmaf(s, w2.y, m[9]);
    m[10] = fmaf(s, w2.z, m[10]); m[11] = fmaf(s, w2.w, m[11]);
    m[12] = fmaf(s, w3.x, m[12]); m[13] = fmaf(s, w3.y, m[13]);
    m[14] = fmaf(s, w3.z, m[14]); m[15] = fmaf(s, w3.w, m[15]);
  }
  int node = dst_unique[li * U_ + u];
  const float4* bp = (const float4*)(bias + (size_t)node * 16);
  float4 b0 = bp[0], b1 = bp[1], b2 = bp[2], b3 = bp[3];
  float bb[16] = {b0.x, b0.y, b0.z, b0.w, b1.x, b1.y, b1.z, b1.w,
                  b2.x, b2.y, b2.z, b2.w, b3.x, b3.y, b3.z, b3.w};
  float4 o0, o1;
  __half2* ov0 = reinterpret_cast<__half2*>(&o0);
  __half2* ov1 = reinterpret_cast<__half2*>(&o1);
#pragma unroll
  for (int k = 0; k < 4; ++k) {
    ov0[k] = __float22half2_rn(make_float2(tanh_fast(m[2 * k] + bb[2 * k]),
                                           tanh_fast(m[2 * k + 1] + bb[2 * k + 1])));
    ov1[k] = __float22half2_rn(make_float2(tanh_fast(m[8 + 2 * k] + bb[8 + 2 * k]),
                                           tanh_fast(m[8 + 2 * k + 1] + bb[8 + 2 * k + 1])));
  }
  h4[(size_t)node * F + b * 2] = o0;
  h4[(size_t)node * F + b * 2 + 1] = o1;
}

__global__ __launch_bounds__(64) void head_c(
    const float4* __restrict__ h4, const float* __restrict__ W_head,
    const float* __restrict__ b_head, const int* __restrict__ root_ids,
    float* __restrict__ out) {
  int bl = blockIdx.x;
  int r = threadIdx.x;
  int node = root_ids[r];
  float4 p0 = h4[(size_t)node * F + bl * 2];
  float4 p1 = h4[(size_t)node * F + bl * 2 + 1];
  float v[16];
  const __half2* ph0 = reinterpret_cast<const __half2*>(&p0);
  const __half2* ph1 = reinterpret_cast<const __half2*>(&p1);
#pragma unroll
  for (int k = 0; k < 4; ++k) {
    float2 f0 = __half22float2(ph0[k]);
    float2 f1 = __half22float2(ph1[k]);
    v[2 * k] = f0.x; v[2 * k + 1] = f0.y;
    v[8 + 2 * k] = f1.x; v[8 + 2 * k + 1] = f1.y;
  }
  float acc0 = 0.f, acc1 = 0.f;
#pragma unroll
  for (int d = 0; d < 16; ++d) {
    acc0 = fmaf(v[d], W_head[r * 16 + d], acc0);
    acc1 = fmaf(v[d], W_head[1024 + r * 16 + d], acc1);
  }
  for (int off = 32; off; off >>= 1) {
    acc0 += __shfl_down(acc0, off, 64);
    acc1 += __shfl_down(acc1, off, 64);
  }
  if (r == 0) {
    out[bl * 2 + 0] = acc0 + b_head[0];
    out[bl * 2 + 1] = acc1 + b_head[1];
  }
}

__global__ void zero_out_k(float* out, int n) {
  int t = blockIdx.x * 256 + threadIdx.x;
  if (t < n) out[t] = 0.f;
}

// ---------------- Host side ----------------

static size_t csr_aux_bytes() {
  return (size_t)L_ * U_ * 4 +        // cnt
         (size_t)L_ * (U_ + 1) * 4 +  // offs
         (size_t)L_ * E_ * 4 +        // rank
         (size_t)L_ * EPL_ * 4 +      // ssrc
         (size_t)L_ * EPLG_ * 4;      // ug
}
static size_t arena_bytes() {
  return (size_t)AROWS * FH * 16 + csr_aux_bytes() +
         (size_t)2 * (N_ + 1) * 4 +   // wmask + lw0
         (size_t)L_ * N_ * 4;         // posarr
}
static size_t classic_bytes() {
  return (size_t)(N_ + 1) * F * 16 + (size_t)U_ * F * 16 + csr_aux_bytes();
}

extern "C" void kernel_launch(void* const* d_in, const int* in_sizes, int n_in,
                              void* d_out, int out_size, void* d_ws, size_t ws_size,
                              hipStream_t stream) {
  const float* X = (const float*)d_in[0];
  const float* w_in = (const float*)d_in[1];
  const float* b_in = (const float*)d_in[2];
  const float* W = (const float*)d_in[3];
  const float* bias = (const float*)d_in[4];
  const float* W_head = (const float*)d_in[5];
  const float* b_head = (const float*)d_in[6];
  const int* gene_map = (const int*)d_in[7];
  const int* src = (const int*)d_in[8];
  const int* dst_pos = (const int*)d_in[9];
  const int* dst_unique = (const int*)d_in[10];
  const int* root_ids = (const int*)d_in[11];
  float* out = (float*)d_out;

  dim3 egrid((E_ + 255) / 256, L_);
  const int pf_grid = (L_ * U_ + L_ * 256 + 255) / 256;
  const int gather_grid = (SW + 3) / 4;

  if (ws_size >= arena_bytes()) {
    // ---------- Arena path: fused gather+dense, two batch halves ----------
    char* ws = (char*)d_ws;
    float4* arena = (float4*)ws;
    size_t off = (size_t)AROWS * FH * 16;
    int* cnt = (int*)(ws + off);    off += (size_t)L_ * U_ * 4;
    int* offs = (int*)(ws + off);   off += (size_t)L_ * (U_ + 1) * 4;
    int* rank = (int*)(ws + off);   off += (size_t)L_ * E_ * 4;
    int* ssrc = (int*)(ws + off);   off += (size_t)L_ * EPL_ * 4;
    int* ug = (int*)(ws + off);     off += (size_t)L_ * EPLG_ * 4;
    int* wmask = (int*)(ws + off);  off += (size_t)(N_ + 1) * 4;
    int* lw0 = (int*)(ws + off);    off += (size_t)(N_ + 1) * 4;
    int* posarr = (int*)(ws + off);

    hipMemsetAsync(cnt, 0, (size_t)L_ * U_ * 4, stream);
    hipMemsetAsync(ug, 0xFF, (size_t)L_ * EPLG_ * 4, stream);
    hipMemsetAsync(wmask, 0, (size_t)2 * (N_ + 1) * 4, stream);  // wmask+lw0
    hipMemsetAsync(arena, 0, (size_t)FH * 16, stream);           // zero row only

    hist_kernel<<<egrid, 256, 0, stream>>>(dst_pos, cnt, rank);
    scan_kernel<<<L_, 1024, 0, stream>>>(cnt, offs);
    scatter_kernel<<<egrid, 256, 0, stream>>>(dst_pos, src, offs, rank, ssrc);
    pad_fill_ug_k<<<pf_grid, 256, 0, stream>>>(cnt, offs, ssrc, ug);
    mark_k<<<(L_ * U_ + G_ + 255) / 256, 256, 0, stream>>>(dst_unique, gene_map,
                                                           wmask, posarr, lw0);
    dim3 rgrid((EPL_ + 255) / 256, L_);
    remap_k<<<rgrid, 256, 0, stream>>>(offs, wmask, posarr, lw0, ssrc);

    for (int half = 0; half < 2; ++half) {
      gene_a<<<(G_ * HBC + 255) / 256, 256, 0, stream>>>(X, w_in, b_in, arena,
                                                         half);
      for (int li = 0; li < L_; ++li) {
        gfused_a<<<gather_grid, 256, 0, stream>>>(arena, ug, ssrc, W, bias,
                                                  dst_unique, arena, li);
      }
      head_a<<<HBC, 64, 0, stream>>>(arena, W_head, b_head, root_ids, wmask,
                                     posarr, lw0, half, out);
    }
  } else if (ws_size >= classic_bytes()) {
    // ---------- Classic path (round-5 proven) ----------
    const size_t h_bytes = (size_t)(N_ + 1) * F * 16;
    const size_t agg_bytes = (size_t)U_ * F * 16;
    char* ws = (char*)d_ws;
    float4* h4 = (float4*)ws;
    float4* agg4 = (float4*)(ws + h_bytes);
    size_t off = h_bytes + agg_bytes;
    int* cnt = (int*)(ws + off);  off += (size_t)L_ * U_ * 4;
    int* offs = (int*)(ws + off); off += (size_t)L_ * (U_ + 1) * 4;
    int* rank = (int*)(ws + off); off += (size_t)L_ * E_ * 4;
    int* ssrc = (int*)(ws + off); off += (size_t)L_ * EPL_ * 4;
    int* ug = (int*)(ws + off);

    hipMemsetAsync(cnt, 0, (size_t)L_ * U_ * 4, stream);
    hipMemsetAsync(ug, 0xFF, (size_t)L_ * EPLG_ * 4, stream);
    hipMemsetAsync(h4, 0, h_bytes, stream);
    hist_kernel<<<egrid, 256, 0, stream>>>(dst_pos, cnt, rank);
    scan_kernel<<<L_, 1024, 0, stream>>>(cnt, offs);
    scatter_kernel<<<egrid, 256, 0, stream>>>(dst_pos, src, offs, rank, ssrc);
    pad_fill_ug_k<<<pf_grid, 256, 0, stream>>>(cnt, offs, ssrc, ug);
    gene_c<<<(G_ * BC + 255) / 256, 256, 0, stream>>>(X, w_in, b_in, gene_map, h4);
    const int dense_grid = U_ * BC / 256;
    for (int li = 0; li < L_; ++li) {
      gather_c<<<gather_grid, 256, 0, stream>>>(h4, ug, ssrc, agg4, li);
      dense_c<<<dense_grid, 256, 0, stream>>>(agg4, W, bias, dst_unique, h4, li);
    }
    head_c<<<BC, 64, 0, stream>>>(h4, W_head, b_head, root_ids, out);
  } else {
    zero_out_k<<<(out_size + 255) / 256, 256, 0, stream>>>(out, out_size);
  }
}